// Round 5
// baseline (993.894 us; speedup 1.0000x reference)
//
#include <hip/hip_runtime.h>

// WaveNet block: B=16, C=256, T=4096, LAYERS=8, K=2 (causal, dilation 2^l).
// R5: two-phase barrier-free K-loop. Phase 1 = filter GEMM (acc 64 AGPR,
// bias preloaded), F packed to bf16 in 32 VGPRs; phase 2 = gate GEMM reusing
// the 64 AGPRs. Total acc footprint 96 regs -> 3 waves/SIMD.
// A-fragments direct global->VGPR from packed weights; B direct from Xin.
// Cheap epilogue: z=(a-1)*rcp((a+1)(1+b)). fp16 Zacc [b][t][c], final transpose.

typedef __attribute__((ext_vector_type(8))) short s16x8;
typedef __attribute__((ext_vector_type(4))) short s16x4;
typedef __attribute__((ext_vector_type(4))) float f32x4;
typedef __attribute__((ext_vector_type(8))) _Float16 h16x8;

#define NB 16
#define NC 256
#define NT 4096
#define TPAD 4224   // 128 (zero pad) + 4096
#define PADT 128
#define NLAYERS 8
#define KTOT 512    // C * Ktap

__device__ __forceinline__ short f2bf(float x) {
  union { float f; unsigned u; } v; v.f = x;
  return (short)((v.u + 0x8000u) >> 16);        // round-half-up
}
__device__ __forceinline__ float bf2f(short s) {
  union { float f; unsigned u; } v; v.u = ((unsigned)(unsigned short)s) << 16;
  return v.f;
}
__device__ __forceinline__ unsigned pk2(float lo, float hi) {
  union { float f; unsigned u; } a, b; a.f = lo; b.f = hi;
  return (((b.u + 0x8000u) >> 16) << 16) | ((a.u + 0x8000u) >> 16);
}

// ---------------- prep kernels ----------------

__global__ void zero_pads(short* __restrict__ base, int nbuf, size_t strideSh) {
  int idx = blockIdx.x * 256 + threadIdx.x;
  if (idx >= nbuf * NB * PADT * NC) return;
  int j = idx >> 19;
  int rem = idx & 524287;
  int b = rem >> 15;
  int r2 = rem & 32767;
  base[(size_t)j * strideSh + (size_t)b * TPAD * NC + r2] = 0;
}

// ys [b][c][t] fp32  ->  X0 [b][128+t][c] bf16 (LDS-tiled transpose)
__global__ void transpose_cast(const float* __restrict__ ys, short* __restrict__ X0) {
  __shared__ float tile[64][65];
  const int b = blockIdx.z, c0 = blockIdx.y * 64, t0 = blockIdx.x * 64;
  const int tid = threadIdx.x;
#pragma unroll
  for (int i = 0; i < 16; ++i) {
    int c = (tid >> 6) + i * 4;
    int t = tid & 63;
    tile[c][t] = ys[((size_t)(b * NC + c0 + c)) * NT + t0 + t];
  }
  __syncthreads();
#pragma unroll
  for (int i = 0; i < 2; ++i) {
    int q = tid + i * 256;
    int t = q >> 3, cc = (q & 7) * 8;
    s16x8 v;
#pragma unroll
    for (int j = 0; j < 8; ++j) v[j] = f2bf(tile[cc + j][t]);
    *(s16x8*)&X0[((size_t)(b * TPAD + PADT + t0 + t)) * NC + c0 + cc] = v;
  }
}

// weights [l][co][ci][kw] fp32 -> packed MFMA A-fragment order:
// idx = l*131072 + kk*16384 + ks*8192 + mb*2048 + mi*512 + lane*8 + j
// element = W[m = mb*64+mi*16+(lane&15)][k = kk*64+ks*32+(lane>>4)*8+j]
__global__ void convert_w(const float* __restrict__ fw, const float* __restrict__ gw,
                          short* __restrict__ Wf, short* __restrict__ Wg) {
  int idx = blockIdx.x * 256 + threadIdx.x;
  if (idx >= NLAYERS * NC * KTOT) return;
  int j    = idx & 7;
  int lane = (idx >> 3) & 63;
  int mi   = (idx >> 9) & 3;
  int mb   = (idx >> 11) & 3;
  int ks   = (idx >> 13) & 1;
  int kk   = (idx >> 14) & 7;
  int l    = idx >> 17;
  int m = mb * 64 + mi * 16 + (lane & 15);
  int k = kk * 64 + ks * 32 + (lane >> 4) * 8 + j;
  int kw = k >> 8, ci = k & 255;
  int src = ((l * NC + m) * NC + ci) * 2 + kw;
  Wf[idx] = f2bf(fw[src]);
  Wg[idx] = f2bf(gw[src]);
}

// one GEMM phase for one tensor: acc must be pre-initialized (bias)
__device__ __forceinline__ void gemm_phase(const short* __restrict__ pA,
                                           const short* __restrict__ pB0,
                                           const short* __restrict__ pB1,
                                           f32x4 acc[4][4]) {
#pragma unroll
  for (int kw = 0; kw < 2; ++kw) {
    const short* pB = kw ? pB1 : pB0;
#pragma unroll
    for (int kc = 0; kc < 4; ++kc) {
      const int kk = kw * 4 + kc;
#pragma unroll
      for (int ks = 0; ks < 2; ++ks) {
        s16x8 a8[4], b8[4];
#pragma unroll
        for (int mi = 0; mi < 4; ++mi)
          a8[mi] = *(const s16x8*)(pA + kk * 16384 + ks * 8192 + mi * 512);
#pragma unroll
        for (int ni = 0; ni < 4; ++ni)
          b8[ni] = *(const s16x8*)(pB + (size_t)(ni * 16) * NC + kc * 64 + ks * 32);
#pragma unroll
        for (int mi = 0; mi < 4; ++mi)
#pragma unroll
          for (int ni = 0; ni < 4; ++ni)
            acc[mi][ni] = __builtin_amdgcn_mfma_f32_16x16x32_bf16(a8[mi], b8[ni], acc[mi][ni], 0, 0, 0);
      }
    }
  }
}

// ---------------- fused layer kernel ----------------
// grid (2, 32, 16): m-tile, t-tile, batch. 256 threads = 4 waves.
__global__ __launch_bounds__(256, 3)
void wavenet_layer(const short* __restrict__ Xin, short* __restrict__ Xout,
                   const short* __restrict__ Wf, const short* __restrict__ Wg,
                   const float* __restrict__ bia_f, const float* __restrict__ bia_g,
                   _Float16* __restrict__ Zacc, float* __restrict__ Zout,
                   int d, int accinit, int writeXout, int zmode) {
  __shared__ short ZT[128 * 128];               // 32 KB, epilogue only

  const int tid = threadIdx.x;
  const int wave = tid >> 6, lane = tid & 63;
  const int quad = lane >> 4, l16 = lane & 15;
  const int m0 = blockIdx.x * 128, t0 = blockIdx.y * 128, b = blockIdx.z;
  const int wm = wave >> 1, wn = wave & 1;

  const short* pAf = Wf + (blockIdx.x * 2 + wm) * 2048 + lane * 8;
  const short* pAg = Wg + (blockIdx.x * 2 + wm) * 2048 + lane * 8;
  const short* pB1 = Xin + ((size_t)(b * TPAD + PADT + t0 + wn * 64 + l16)) * NC + quad * 8;
  const short* pB0 = pB1 - (size_t)d * NC;      // tap 0 reads x[t-d]

  f32x4 acc[4][4];

  // ---- phase 1: filter ----
#pragma unroll
  for (int mi = 0; mi < 4; ++mi) {
    const float4 bv = *(const float4*)&bia_f[m0 + wm * 64 + mi * 16 + quad * 4];
#pragma unroll
    for (int ni = 0; ni < 4; ++ni)
      acc[mi][ni] = (f32x4){bv.x, bv.y, bv.z, bv.w};
  }
  gemm_phase(pAf, pB0, pB1, acc);

  unsigned fpk[4][4][2];                        // F packed bf16, 32 VGPR
#pragma unroll
  for (int mi = 0; mi < 4; ++mi)
#pragma unroll
    for (int ni = 0; ni < 4; ++ni) {
      fpk[mi][ni][0] = pk2(acc[mi][ni][0], acc[mi][ni][1]);
      fpk[mi][ni][1] = pk2(acc[mi][ni][2], acc[mi][ni][3]);
    }

  // ---- phase 2: gate (reuse acc) ----
#pragma unroll
  for (int mi = 0; mi < 4; ++mi) {
    const float4 bv = *(const float4*)&bia_g[m0 + wm * 64 + mi * 16 + quad * 4];
#pragma unroll
    for (int ni = 0; ni < 4; ++ni)
      acc[mi][ni] = (f32x4){bv.x, bv.y, bv.z, bv.w};
  }
  gemm_phase(pAg, pB0, pB1, acc);

  // -------- epilogue --------
  const float C2 = 2.885390082f;                // 2*log2(e)
  const float C1 = 1.442695041f;                // log2(e)
#pragma unroll
  for (int mi = 0; mi < 4; ++mi) {
#pragma unroll
    for (int ni = 0; ni < 4; ++ni) {
      const int mbase = m0 + wm * 64 + mi * 16 + quad * 4;
      const int tl = wn * 64 + ni * 16 + l16;
      const int t = t0 + tl;
      short pk[4];
#pragma unroll
      for (int r = 0; r < 4; ++r) {
        unsigned fu = fpk[mi][ni][r >> 1];
        union { float f; unsigned u; } fv;
        fv.u = (r & 1) ? (fu & 0xffff0000u) : (fu << 16);
        float f = fv.f;
        f = fminf(fmaxf(f, -30.f), 30.f);
        float g = acc[mi][ni][r];
        float a = __builtin_amdgcn_exp2f(f * C2);
        float bb = __builtin_amdgcn_exp2f(-g * C1);
        float z = (a - 1.f) * __builtin_amdgcn_rcpf((a + 1.f) * (1.f + bb));
        if (zmode) {
          size_t zo = ((size_t)(b * NC + mbase + r)) * NT + t;
          if (zmode == 1) Zout[zo] = z; else Zout[zo] += z;
        }
        pk[r] = f2bf(z);
      }
      // rotate-swizzle: physical col = (c + t*8) & 127
      int cloc = wm * 64 + mi * 16 + quad * 4;
      short* dst = &ZT[tl * 128 + ((cloc + tl * 8) & 127)];
      *(s16x4*)dst = (s16x4){pk[0], pk[1], pk[2], pk[3]};
    }
  }
  __syncthreads();
#pragma unroll
  for (int i = 0; i < 8; ++i) {
    int q = tid + i * 256;                      // 2048 chunks of 16B
    int t = q >> 4, cc = (q & 15) * 8;
    s16x8 v = *(const s16x8*)&ZT[t * 128 + ((cc + t * 8) & 127)];
    if (writeXout)
      *(s16x8*)&Xout[((size_t)(b * TPAD + PADT + t0 + t)) * NC + m0 + cc] = v;
    if (Zacc) {
      size_t zo = ((size_t)(b * NT + t0 + t)) * NC + m0 + cc;
      h16x8* zp = (h16x8*)&Zacc[zo];
      h16x8 h;
      if (accinit) {
#pragma unroll
        for (int e = 0; e < 8; ++e) h[e] = (_Float16)bf2f(v[e]);
      } else {
        h = *zp;
#pragma unroll
        for (int e = 0; e < 8; ++e) h[e] = (_Float16)((float)h[e] + bf2f(v[e]));
      }
      *zp = h;
    }
  }
}

// ---------------- final: transpose fp16 Zacc [b][t][c] -> fp32 Zout [b][c][t] ----------------
__global__ void zacc_to_out(const _Float16* __restrict__ Zacc, float* __restrict__ Zout) {
  __shared__ float tile[64][65];
  const int b = blockIdx.z, c0 = blockIdx.y * 64, t0 = blockIdx.x * 64;
  const int tid = threadIdx.x;
#pragma unroll
  for (int i = 0; i < 2; ++i) {
    int q = tid + i * 256;
    int tl = q >> 3, cc = (q & 7) * 8;
    h16x8 v = *(const h16x8*)&Zacc[((size_t)(b * NT + t0 + tl)) * NC + c0 + cc];
#pragma unroll
    for (int e = 0; e < 8; ++e) tile[tl][cc + e] = (float)v[e];
  }
  __syncthreads();
#pragma unroll
  for (int i = 0; i < 4; ++i) {
    int c = (tid >> 4) + i * 16;
    int t = (tid & 15) * 4;
    float4 v = make_float4(tile[t][c], tile[t + 1][c], tile[t + 2][c], tile[t + 3][c]);
    *(float4*)&Zout[((size_t)(b * NC + c0 + c)) * NT + t0 + t] = v;
  }
}

// ---------------- launch ----------------
extern "C" void kernel_launch(void* const* d_in, const int* in_sizes, int n_in,
                              void* d_out, int out_size, void* d_ws, size_t ws_size,
                              hipStream_t stream) {
  const float* ys = (const float*)d_in[0];
  const float* fw = (const float*)d_in[1];
  const float* fb = (const float*)d_in[2];
  const float* gw = (const float*)d_in[3];
  const float* gb = (const float*)d_in[4];
  float* Zout = (float*)d_out;

  char* ws = (char*)d_ws;
  const size_t xbytes = (size_t)NB * TPAD * NC * 2;
  const size_t strideSh = xbytes / 2;
  const size_t wcount = (size_t)NLAYERS * NC * KTOT;
  const size_t wbytes = 2 * wcount * 2;
  const size_t zaccbytes = (size_t)NB * NT * NC * 2;     // fp16
  const size_t need = 2 * xbytes + zaccbytes + wbytes;   // ~107 MB

  const bool defer = (ws_size >= need);

  short* Xbase = (short*)ws;
  _Float16* Zacc = nullptr;
  short* Wf;
  if (defer) {
    Zacc = (_Float16*)(ws + 2 * xbytes);
    Wf = (short*)(ws + 2 * xbytes + zaccbytes);
  } else {
    Wf = (short*)(ws + 2 * xbytes);
  }
  short* Wg = Wf + wcount;

  {
    int total = 2 * NB * PADT * NC;
    hipLaunchKernelGGL(zero_pads, dim3((total + 255) / 256), dim3(256), 0, stream,
                       Xbase, 2, strideSh);
  }
  hipLaunchKernelGGL(transpose_cast, dim3(64, 4, 16), dim3(256), 0, stream, ys, Xbase);
  hipLaunchKernelGGL(convert_w, dim3(4096), dim3(256), 0, stream, fw, gw, Wf, Wg);

  for (int l = 0; l < NLAYERS; ++l) {
    const short* Xin = (l & 1) ? Xbase + strideSh : Xbase;
    short* Xo = (l & 1) ? Xbase : Xbase + strideSh;
    int accinit = (l == 0) ? 1 : 0;
    int writeXout = (l < NLAYERS - 1) ? 1 : 0;
    int zmode = defer ? 0 : ((l == 0) ? 1 : 2);
    hipLaunchKernelGGL(wavenet_layer, dim3(2, 32, 16), dim3(256), 0, stream,
                       Xin, Xo,
                       Wf + (size_t)l * NC * KTOT, Wg + (size_t)l * NC * KTOT,
                       fb + l * NC, gb + l * NC, Zacc, Zout, 1 << l,
                       accinit, writeXout, zmode);
  }
  if (defer) {
    hipLaunchKernelGGL(zacc_to_out, dim3(64, 4, 16), dim3(256), 0, stream, Zacc, Zout);
  }
}